// Round 5
// baseline (895.593 us; speedup 1.0000x reference)
//
#include <hip/hip_runtime.h>
#include <math.h>

#define LLEN 8192
#define DDIM 1024
#define NB   2
#define NMODE 512
#define MFFT 8192
#define SLEN 4096        // truncated kernel length (K[l]=0 beyond; worst-case e^-20)
#define KF_STRIDE 8208   // float2 per Kf row (8193 used)

// ---------------- workspace layout (bytes), total ~172.4 MB ----------------
#define OFF_UT   ((size_t)0)            // u_T [B,D,L] f32 (y+res in place)  67,108,864
#define OFF_KF   ((size_t)67108864)     // Kf [D,KF_STRIDE] float2           67,239,936
                                        //   (Sr/Si [512][4096] f32 overlaid here
                                        //    before kf_fft runs: 8 MB x2)
#define OFF_KT   ((size_t)134348800)    // K_T [D][SLEN] f32                 16,777,216
#define OFF_CPR  ((size_t)167903232)    // C'r [D,N] f32                      2,097,152
#define OFF_CPI  ((size_t)170000384)    // C'i [D,N] f32                      2,097,152
#define OFF_MEAN ((size_t)172097536)    // mean [B,L] f32                        65,536
#define OFF_RSTD ((size_t)172163072)    // rstd [B,L] f32                        65,536
#define OFF_LAMR ((size_t)172228608)    // f32[512]
#define OFF_LAMID ((size_t)172230656)   // f64[512] (4096 B)
#define OFF_WR   ((size_t)172234752)    // f32[512]
#define OFF_WI   ((size_t)172236800)    // f32[512]
#define OFF_CUT  ((size_t)172238848)    // int[512]
#define OFF_TW   ((size_t)172240896)    // twH: 8192 float2 (hierarchical)      65,536
#define OFF_TWR  ((size_t)172306432)    // 8193 float2 (2pi k/16384)            65,544
#define WS_NEED  ((size_t)172371976)

// Sr/Si overlay inside the KF region (dead until kf_fft writes KF)
#define OFF_SR   OFF_KF
#define OFF_SI   (OFF_KF + (size_t)(NMODE * SLEN * 4))

// ---------------- LayerNorm stats: mean/rstd per (b,l) row ----------------
__global__ __launch_bounds__(256) void ln_stats_kernel(const float* __restrict__ x,
                                                       float* __restrict__ mean,
                                                       float* __restrict__ rstd) {
  __shared__ float red[16];
  int row = blockIdx.x;            // b*L + l
  int tid = threadIdx.x;
  const float4* xr = (const float4*)(x + (size_t)row * DDIM);
  float4 v = xr[tid];
  float s = v.x + v.y + v.z + v.w;
  float q = v.x*v.x + v.y*v.y + v.z*v.z + v.w*v.w;
  #pragma unroll
  for (int off = 32; off; off >>= 1) { s += __shfl_down(s, off); q += __shfl_down(q, off); }
  int wid = tid >> 6;
  if ((tid & 63) == 0) { red[wid] = s; red[8 + wid] = q; }
  __syncthreads();
  if (tid == 0) {
    float ts = red[0] + red[1] + red[2] + red[3];
    float tq = red[8] + red[9] + red[10] + red[11];
    float m = ts * (1.0f / DDIM);
    float var = tq * (1.0f / DDIM) - m * m;
    mean[row] = m;
    rstd[row] = rsqrtf(var + 1e-5f);
  }
}

// ---------------- fused LN + transpose: x[B,L,D] -> uT[B,D,L] ----------------
__global__ __launch_bounds__(256) void transpose_ln_kernel(const float* __restrict__ x,
                                                           const float* __restrict__ mean,
                                                           const float* __restrict__ rstd,
                                                           const float* __restrict__ gamma,
                                                           const float* __restrict__ beta,
                                                           float* __restrict__ uT) {
  __shared__ float tile[32][33];
  int lt = blockIdx.x * 32, dt = blockIdx.y * 32, b = blockIdx.z;
  int c = threadIdx.x & 31, r0 = threadIdx.x >> 5;
  float gv = gamma[dt + c], bv = beta[dt + c];
  #pragma unroll
  for (int i = 0; i < 4; i++) {
    int r = r0 + i * 8;   // l within tile
    float m = mean[(size_t)b * LLEN + lt + r];
    float rs = rstd[(size_t)b * LLEN + lt + r];
    float xv = x[((size_t)b * LLEN + lt + r) * DDIM + dt + c];
    tile[r][c] = (xv - m) * rs * gv + bv;
  }
  __syncthreads();
  #pragma unroll
  for (int i = 0; i < 4; i++) {
    int r = r0 + i * 8;   // d within tile
    uT[((size_t)b * DDIM + dt + r) * LLEN + lt + c] = tile[c][r];
  }
}

// ---------------- params + twiddle tables (all one-time, double precision) ----------------
__global__ void build_tables_kernel(const float* __restrict__ Lr, const float* __restrict__ Li,
                                    float* lamr, double* lamid, float* wre, float* wim, int* cut,
                                    float2* twH, float2* twR) {
  int gid = blockIdx.x * 256 + threadIdx.x;
  if (gid < NMODE) {
    double lr = (double)Lr[gid], li = (double)Li[gid];
    double ar = -exp(lr);      // Re(Lam)  (negative)
    double ai = exp(li);       // Im(Lam)
    lamr[gid] = (float)ar;
    lamid[gid] = ai;
    double em = exp(ar);
    double cs = cos(ai), sn = sin(ai);
    double er = em * cs - 1.0;     // exp(Lam) - 1
    double ei = em * sn;
    double den = ar * ar + ai * ai;
    wre[gid] = (float)((er * ar + ei * ai) / den);   // (exp(Lam)-1)/Lam
    wim[gid] = (float)((ei * ar - er * ai) / den);
    int co = (int)(40.0 / (-ar)) + 1;                // exp(ar*l) < e^-40 beyond
    cut[gid] = co > SLEN ? SLEN : co;                // clamp to truncated domain
  }
  int j = gid - NMODE;
  if (j >= 0 && j < 8192) {
    // hierarchical twiddle: twH[Ls + p] = (cos(pi*p/Ls), +sin(pi*p/Ls)).
    // Core applies wi = sign*w.y: sign=-1 (fwd) -> e^{-i a}, sign=+1 (inv) -> e^{+i a}.
    if (j == 0) {
      twH[0] = make_float2(1.f, 0.f);
    } else {
      int lev = 31 - __clz(j);
      int Ls = 1 << lev;
      int p = j - Ls;
      double a = 3.14159265358979323846264338 * (double)p / (double)Ls;
      twH[j] = make_float2((float)cos(a), (float)sin(a));
    }
  }
  int k = gid - (NMODE + 8192);
  if (k >= 0 && k <= 8192) {
    double a = 6.283185307179586476925287 * (double)k / 16384.0;
    twR[k] = make_float2((float)cos(a), (float)sin(a));
  }
}

// ---------------- C' = (Cr + iCi) * W ----------------
__global__ __launch_bounds__(256) void cprime_kernel(const float* __restrict__ Cr,
                                                     const float* __restrict__ Ci,
                                                     const float* __restrict__ wre,
                                                     const float* __restrict__ wim,
                                                     float* __restrict__ Cpr,
                                                     float* __restrict__ Cpi) {
  int idx = blockIdx.x * 256 + threadIdx.x;   // d*N + n
  int n = idx & (NMODE - 1);
  float cr = Cr[idx], ci = Ci[idx];
  float wr = wre[n], wi = wim[n];
  Cpr[idx] = cr * wr - ci * wi;
  Cpi[idx] = cr * wi + ci * wr;
}

// ---------------- S[n,l] = exp(Lam_n l), zero-padded beyond cut, l < SLEN ----------------
__global__ __launch_bounds__(256) void sbuild_kernel(const float* __restrict__ lamr,
                                                     const double* __restrict__ lamid,
                                                     const int* __restrict__ cut,
                                                     float* __restrict__ Sr,
                                                     float* __restrict__ Si) {
  int n = blockIdx.y;
  int l = blockIdx.x * 256 + threadIdx.x;
  float sr = 0.f, si = 0.f;
  if (l < cut[n]) {
    float mag = expf(lamr[n] * (float)l);
    double ph = lamid[n] * (double)l;
    const double tp = 6.283185307179586476925287;
    const double itp = 1.0 / 6.283185307179586476925287;
    ph -= floor(ph * itp) * tp;
    float cs, sn; sincosf((float)ph, &sn, &cs);
    sr = mag * cs; si = mag * sn;
  }
  Sr[(size_t)n * SLEN + l] = sr;
  Si[(size_t)n * SLEN + l] = si;
}

// ---------------- KT[d,l] = sum_n Cpr[d,n]*Sr[n,l] - Cpi[d,n]*Si[n,l] ----------------
// Flat: one block per (d, l-tile of 1024). Thread owns 4 consecutive l (float4 IO).
#define KB3_LT 1024
__global__ __launch_bounds__(256) void kbuild3_kernel(const float* __restrict__ Sr,
                                                      const float* __restrict__ Si,
                                                      const float* __restrict__ Cpr,
                                                      const float* __restrict__ Cpi,
                                                      const int* __restrict__ cut,
                                                      float* __restrict__ KT) {
  __shared__ float sCr[NMODE], sCi[NMODE];
  __shared__ int scut[NMODE];
  int tid = threadIdx.x;
  int l0 = blockIdx.x * KB3_LT;
  int d  = blockIdx.y;
  for (int i = tid; i < NMODE; i += 256) {
    scut[i] = cut[i];
    sCr[i] = Cpr[(size_t)d * NMODE + i];
    sCi[i] = Cpi[(size_t)d * NMODE + i];
  }
  __syncthreads();
  float4 acc = make_float4(0.f, 0.f, 0.f, 0.f);
  int li = l0 / 4 + tid;   // float4 index within S/KT rows
  for (int n = 0; n < NMODE; ++n) {
    if (scut[n] <= l0) continue;          // block-uniform skip (S zero-padded => exact)
    float4 s_r = ((const float4*)(Sr + (size_t)n * SLEN))[li];
    float4 s_i = ((const float4*)(Si + (size_t)n * SLEN))[li];
    float cr = sCr[n], ci = sCi[n];
    acc.x += s_r.x * cr - s_i.x * ci;
    acc.y += s_r.y * cr - s_i.y * ci;
    acc.z += s_r.z * cr - s_i.z * ci;
    acc.w += s_r.w * cr - s_i.w * ci;
  }
  ((float4*)(KT + (size_t)d * SLEN))[li] = acc;
}

// ---------------- 8192-pt complex Stockham FFT in LDS ----------------
// natural order in/out; result ends in bufB. sign=-1 fwd, +1 inv (unnormalized).
// twH[Ls+p] = (cos(pi p/Ls), +sin(pi p/Ls)); effective twiddle = (w.x, sign*w.y).
__device__ __forceinline__ void fft8192_core(float2* bufA, float2* bufB,
                                             const float2* __restrict__ twH,
                                             int tid, float sign) {
  float2* src = bufA;
  float2* dst = bufB;
  #pragma unroll 1
  for (int s = 0; s < 13; ++s) {
    int Ls = 1 << s;
    __syncthreads();
    #pragma unroll
    for (int it = 0; it < 4; ++it) {
      int j = tid + it * 1024;            // butterfly id < 4096
      int p = j & (Ls - 1);
      int q = j >> s;
      float2 w = twH[Ls + p];
      float wr = w.x, wi = sign * w.y;    // fwd: e^{-ia}, inv: e^{+ia}
      float2 a = src[j];
      float2 b = src[j + 4096];
      float br = wr * b.x - wi * b.y;
      float bi = wr * b.y + wi * b.x;
      int o = (q << (s + 1)) + p;
      dst[o]      = make_float2(a.x + br, a.y + bi);
      dst[o + Ls] = make_float2(a.x - br, a.y - bi);
    }
    float2* tsw = src; src = dst; dst = tsw;
  }
  __syncthreads();
}

// ---------------- Kf[d,k] = rfft16384(K_T[d]) / 8192, k=0..8192 ----------------
__global__ __launch_bounds__(1024) void kf_fft_kernel(const float* __restrict__ KT,
                                                      const float2* __restrict__ twH,
                                                      const float2* __restrict__ twR,
                                                      float2* __restrict__ Kf) {
  __shared__ float2 bufA[MFFT];
  __shared__ float2 bufB[MFFT];
  int d = blockIdx.x;
  int tid = threadIdx.x;
  const float2* row = (const float2*)(KT + (size_t)d * SLEN);
  for (int j = tid; j < MFFT; j += 1024)
    bufA[j] = (j < SLEN / 2) ? row[j] : make_float2(0.f, 0.f);
  fft8192_core(bufA, bufB, twH, tid, -1.f);   // Z in bufB
  const float scale = 1.0f / 8192.0f;         // fold inverse-FFT 1/8192 here
  float2* out = Kf + (size_t)d * KF_STRIDE;
  for (int k = tid; k <= 4096; k += 1024) {
    if (k == 0) {
      float2 z0 = bufB[0];
      out[0]    = make_float2((z0.x + z0.y) * scale, 0.f);
      out[8192] = make_float2((z0.x - z0.y) * scale, 0.f);
    } else {
      float2 zk = bufB[k];
      float2 zm = bufB[MFFT - k];
      float Ar = 0.5f * (zk.x + zm.x), Ai = 0.5f * (zk.y - zm.y);
      float Br = 0.5f * (zk.x - zm.x), Bi = 0.5f * (zk.y + zm.y);
      float2 t = twR[k];
      float c = t.x, sn = t.y;
      float e1r = sn * Br - c * Bi;
      float e1i = sn * Bi + c * Br;
      out[k]        = make_float2((Ar - e1r) * scale, (Ai - e1i) * scale);
      out[MFFT - k] = make_float2((Ar + e1r) * scale, (-Ai - e1i) * scale);
    }
  }
}

// ---------------- conv: y = irfft(rfft(u) * Kf) + u*pD, in-place over uT row ----------------
__global__ __launch_bounds__(1024) void conv_fft_kernel(float* __restrict__ uT,
                                                        const float2* __restrict__ twH,
                                                        const float2* __restrict__ twR,
                                                        const float2* __restrict__ Kf,
                                                        const float* __restrict__ pD) {
  __shared__ float2 bufA[MFFT];
  __shared__ float2 bufB[MFFT];
  int wg = blockIdx.x;
  int b = wg >> 10, d = wg & (DDIM - 1);
  int tid = threadIdx.x;
  float2* row = (float2*)(uT + ((size_t)b * DDIM + d) * LLEN);
  for (int j = tid; j < MFFT; j += 1024)
    bufA[j] = (j < 4096) ? row[j] : make_float2(0.f, 0.f);
  fft8192_core(bufA, bufB, twH, tid, -1.f);   // Z in bufB
  const float2* kf = Kf + (size_t)d * KF_STRIDE;
  for (int k = tid; k <= 4096; k += 1024) {
    if (k == 0) {
      float2 z0 = bufB[0];
      float U0 = z0.x + z0.y;
      float UM = z0.x - z0.y;
      float Y0 = U0 * kf[0].x;
      float YM = UM * kf[8192].x;
      bufA[0] = make_float2(0.5f * (Y0 + YM), 0.5f * (Y0 - YM));
    } else {
      float2 zk = bufB[k];
      float2 zm = bufB[MFFT - k];
      float Ar = 0.5f * (zk.x + zm.x), Ai = 0.5f * (zk.y - zm.y);
      float Br = 0.5f * (zk.x - zm.x), Bi = 0.5f * (zk.y + zm.y);
      float2 t = twR[k];
      float c = t.x, sn = t.y;
      float e1r = sn * Br - c * Bi;
      float e1i = sn * Bi + c * Br;
      float Ukr = Ar - e1r, Uki = Ai - e1i;      // U[k]
      float Umr = Ar + e1r, Umi = -Ai - e1i;     // U[8192-k]
      float2 kk = kf[k], km = kf[MFFT - k];
      float Ykr = Ukr * kk.x - Uki * kk.y, Yki = Ukr * kk.y + Uki * kk.x;
      float Ymr = Umr * km.x - Umi * km.y, Ymi = Umr * km.y + Umi * km.x;
      float Eyr = 0.5f * (Ykr + Ymr), Eyi = 0.5f * (Yki - Ymi);
      float Byr = 0.5f * (Ykr - Ymr), Byi = 0.5f * (Yki + Ymi);
      bufA[k]        = make_float2(Eyr - sn * Byr - c * Byi, Eyi + c * Byr - sn * Byi);
      bufA[MFFT - k] = make_float2(Eyr + sn * Byr + c * Byi, -Eyi + c * Byr - sn * Byi);
    }
  }
  __syncthreads();
  fft8192_core(bufA, bufB, twH, tid, +1.f);   // z_y in bufB (1/8192 folded into Kf)
  float pdv = pD[d];
  for (int j = tid; j < 4096; j += 1024) {
    float2 uv = row[j];                        // original u (untouched so far)
    float2 yv = bufB[j];
    row[j] = make_float2(yv.x + uv.x * pdv, yv.y + uv.y * pdv);
  }
}

// ---------------- out[b,l,d] = yT[b,d,l] (transpose back) ----------------
__global__ __launch_bounds__(256) void final_kernel(const float* __restrict__ yT,
                                                    float* __restrict__ out) {
  __shared__ float tile[32][33];
  int lt = blockIdx.x * 32, dt = blockIdx.y * 32, b = blockIdx.z;
  int c = threadIdx.x & 31, r0 = threadIdx.x >> 5;
  #pragma unroll
  for (int i = 0; i < 4; i++) {
    int r = r0 + i * 8;   // d within tile
    tile[r][c] = yT[((size_t)b * DDIM + dt + r) * LLEN + lt + c];
  }
  __syncthreads();
  #pragma unroll
  for (int i = 0; i < 4; i++) {
    int r = r0 + i * 8;   // l within tile
    out[((size_t)b * LLEN + lt + r) * DDIM + dt + c] = tile[c][r];
  }
}

extern "C" void kernel_launch(void* const* d_in, const int* in_sizes, int n_in,
                              void* d_out, int out_size, void* d_ws, size_t ws_size,
                              hipStream_t stream) {
  (void)in_sizes; (void)n_in; (void)out_size;
  if (ws_size < WS_NEED) return;   // safety: fail cleanly (wrong output) instead of faulting
  const float* x     = (const float*)d_in[0];
  const float* Lr    = (const float*)d_in[1];
  const float* Li    = (const float*)d_in[2];
  const float* Cr    = (const float*)d_in[3];
  const float* Ci    = (const float*)d_in[4];
  const float* pD    = (const float*)d_in[5];
  const float* gamma = (const float*)d_in[6];
  const float* beta  = (const float*)d_in[7];
  float* out = (float*)d_out;
  char* ws = (char*)d_ws;

  float*  UT    = (float*)(ws + OFF_UT);
  float2* KF    = (float2*)(ws + OFF_KF);
  float*  SRb   = (float*)(ws + OFF_SR);    // overlaid on KF region
  float*  SIb   = (float*)(ws + OFF_SI);    // overlaid on KF region
  float*  KT    = (float*)(ws + OFF_KT);
  float*  CPR   = (float*)(ws + OFF_CPR);
  float*  CPI   = (float*)(ws + OFF_CPI);
  float*  MEAN  = (float*)(ws + OFF_MEAN);
  float*  RSTD  = (float*)(ws + OFF_RSTD);
  float*  LAMR  = (float*)(ws + OFF_LAMR);
  double* LAMID = (double*)(ws + OFF_LAMID);
  float*  WRe   = (float*)(ws + OFF_WR);
  float*  WIm   = (float*)(ws + OFF_WI);
  int*    CUT   = (int*)(ws + OFF_CUT);
  float2* TWH   = (float2*)(ws + OFF_TW);
  float2* TWR   = (float2*)(ws + OFF_TWR);

  ln_stats_kernel<<<NB * LLEN, 256, 0, stream>>>(x, MEAN, RSTD);
  transpose_ln_kernel<<<dim3(LLEN / 32, DDIM / 32, NB), 256, 0, stream>>>(x, MEAN, RSTD, gamma, beta, UT);
  build_tables_kernel<<<67, 256, 0, stream>>>(Lr, Li, LAMR, LAMID, WRe, WIm, CUT, TWH, TWR);
  cprime_kernel<<<(DDIM * NMODE) / 256, 256, 0, stream>>>(Cr, Ci, WRe, WIm, CPR, CPI);
  sbuild_kernel<<<dim3(SLEN / 256, NMODE), 256, 0, stream>>>(LAMR, LAMID, CUT, SRb, SIb);
  kbuild3_kernel<<<dim3(SLEN / KB3_LT, DDIM), 256, 0, stream>>>(SRb, SIb, CPR, CPI, CUT, KT);
  kf_fft_kernel<<<DDIM, 1024, 0, stream>>>(KT, TWH, TWR, KF);   // KF overwrites S region (S dead now)
  conv_fft_kernel<<<NB * DDIM, 1024, 0, stream>>>(UT, TWH, TWR, KF, pD);
  final_kernel<<<dim3(LLEN / 32, DDIM / 32, NB), 256, 0, stream>>>(UT, out);
}

// Round 6
// 563.160 us; speedup vs baseline: 1.5903x; 1.5903x over previous
//
#include <hip/hip_runtime.h>
#include <math.h>

#define LLEN 8192
#define DDIM 1024
#define NB   2
#define NMODE 512
#define MFFT 8192
#define SLEN 4096        // truncated kernel length (K[l]=0 beyond; worst-case e^-20)
#define KF_STRIDE 8208   // float2 per Kf row (8193 used)

// ---------------- workspace layout (bytes), total ~172.4 MB ----------------
#define OFF_UT   ((size_t)0)            // u_T [B,D,L] f32 (y+res in place)  67,108,864
#define OFF_KF   ((size_t)67108864)     // Kf [D,KF_STRIDE] float2           67,239,936
                                        //   (Sr/Si [512][4096] f32 overlaid here
                                        //    before kf_fft runs: 8 MB x2)
#define OFF_KT   ((size_t)134348800)    // K_T [D][SLEN] f32                 16,777,216
#define OFF_CPR  ((size_t)167903232)    // C'r [D,N] f32                      2,097,152
#define OFF_CPI  ((size_t)170000384)    // C'i [D,N] f32                      2,097,152
#define OFF_MEAN ((size_t)172097536)    // mean [B,L] f32                        65,536
#define OFF_RSTD ((size_t)172163072)    // rstd [B,L] f32                        65,536
#define OFF_LAMR ((size_t)172228608)    // f32[512]
#define OFF_LAMID ((size_t)172230656)   // f64[512] (4096 B)
#define OFF_WR   ((size_t)172234752)    // f32[512]
#define OFF_WI   ((size_t)172236800)    // f32[512]
#define OFF_CUT  ((size_t)172238848)    // int[512]
#define OFF_TW   ((size_t)172240896)    // twH: 8192 float2 (hierarchical)      65,536
#define OFF_TWR  ((size_t)172306432)    // 8193 float2 (2pi k/16384)            65,544
#define OFF_MLIST ((size_t)172371976)   // int[16][512] per-l-tile active modes  32,768
#define OFF_MCNT  ((size_t)172404744)   // int[16]                                   64
#define WS_NEED  ((size_t)172404808)

// Sr/Si overlay inside the KF region (dead until kf_fft writes KF)
#define OFF_SR   OFF_KF
#define OFF_SI   (OFF_KF + (size_t)(NMODE * SLEN * 4))

// ---------------- LayerNorm stats: mean/rstd per (b,l) row ----------------
__global__ __launch_bounds__(256) void ln_stats_kernel(const float* __restrict__ x,
                                                       float* __restrict__ mean,
                                                       float* __restrict__ rstd) {
  __shared__ float red[16];
  int row = blockIdx.x;            // b*L + l
  int tid = threadIdx.x;
  const float4* xr = (const float4*)(x + (size_t)row * DDIM);
  float4 v = xr[tid];
  float s = v.x + v.y + v.z + v.w;
  float q = v.x*v.x + v.y*v.y + v.z*v.z + v.w*v.w;
  #pragma unroll
  for (int off = 32; off; off >>= 1) { s += __shfl_down(s, off); q += __shfl_down(q, off); }
  int wid = tid >> 6;
  if ((tid & 63) == 0) { red[wid] = s; red[8 + wid] = q; }
  __syncthreads();
  if (tid == 0) {
    float ts = red[0] + red[1] + red[2] + red[3];
    float tq = red[8] + red[9] + red[10] + red[11];
    float m = ts * (1.0f / DDIM);
    float var = tq * (1.0f / DDIM) - m * m;
    mean[row] = m;
    rstd[row] = rsqrtf(var + 1e-5f);
  }
}

// ---------------- fused LN + transpose: x[B,L,D] -> uT[B,D,L] ----------------
__global__ __launch_bounds__(256) void transpose_ln_kernel(const float* __restrict__ x,
                                                           const float* __restrict__ mean,
                                                           const float* __restrict__ rstd,
                                                           const float* __restrict__ gamma,
                                                           const float* __restrict__ beta,
                                                           float* __restrict__ uT) {
  __shared__ float tile[32][33];
  int lt = blockIdx.x * 32, dt = blockIdx.y * 32, b = blockIdx.z;
  int c = threadIdx.x & 31, r0 = threadIdx.x >> 5;
  float gv = gamma[dt + c], bv = beta[dt + c];
  #pragma unroll
  for (int i = 0; i < 4; i++) {
    int r = r0 + i * 8;   // l within tile
    float m = mean[(size_t)b * LLEN + lt + r];
    float rs = rstd[(size_t)b * LLEN + lt + r];
    float xv = x[((size_t)b * LLEN + lt + r) * DDIM + dt + c];
    tile[r][c] = (xv - m) * rs * gv + bv;
  }
  __syncthreads();
  #pragma unroll
  for (int i = 0; i < 4; i++) {
    int r = r0 + i * 8;   // d within tile
    uT[((size_t)b * DDIM + dt + r) * LLEN + lt + c] = tile[c][r];
  }
}

// ---------------- params + twiddle tables (all one-time, double precision) ----------------
__global__ void build_tables_kernel(const float* __restrict__ Lr, const float* __restrict__ Li,
                                    float* lamr, double* lamid, float* wre, float* wim, int* cut,
                                    float2* twH, float2* twR) {
  int gid = blockIdx.x * 256 + threadIdx.x;
  if (gid < NMODE) {
    double lr = (double)Lr[gid], li = (double)Li[gid];
    double ar = -exp(lr);      // Re(Lam)  (negative)
    double ai = exp(li);       // Im(Lam)
    lamr[gid] = (float)ar;
    lamid[gid] = ai;
    double em = exp(ar);
    double cs = cos(ai), sn = sin(ai);
    double er = em * cs - 1.0;     // exp(Lam) - 1
    double ei = em * sn;
    double den = ar * ar + ai * ai;
    wre[gid] = (float)((er * ar + ei * ai) / den);   // (exp(Lam)-1)/Lam
    wim[gid] = (float)((ei * ar - er * ai) / den);
    int co = (int)(40.0 / (-ar)) + 1;                // exp(ar*l) < e^-40 beyond
    cut[gid] = co > SLEN ? SLEN : co;                // clamp to truncated domain
  }
  int j = gid - NMODE;
  if (j >= 0 && j < 8192) {
    // hierarchical twiddle: twH[Ls + p] = (cos(pi*p/Ls), +sin(pi*p/Ls)).
    // Core applies wi = sign*w.y: sign=-1 (fwd) -> e^{-i a}, sign=+1 (inv) -> e^{+i a}.
    if (j == 0) {
      twH[0] = make_float2(1.f, 0.f);
    } else {
      int lev = 31 - __clz(j);
      int Ls = 1 << lev;
      int p = j - Ls;
      double a = 3.14159265358979323846264338 * (double)p / (double)Ls;
      twH[j] = make_float2((float)cos(a), (float)sin(a));
    }
  }
  int k = gid - (NMODE + 8192);
  if (k >= 0 && k <= 8192) {
    double a = 6.283185307179586476925287 * (double)k / 16384.0;
    twR[k] = make_float2((float)cos(a), (float)sin(a));
  }
}

// ---------------- C' = (Cr + iCi) * W ----------------
__global__ __launch_bounds__(256) void cprime_kernel(const float* __restrict__ Cr,
                                                     const float* __restrict__ Ci,
                                                     const float* __restrict__ wre,
                                                     const float* __restrict__ wim,
                                                     float* __restrict__ Cpr,
                                                     float* __restrict__ Cpi) {
  int idx = blockIdx.x * 256 + threadIdx.x;   // d*N + n
  int n = idx & (NMODE - 1);
  float cr = Cr[idx], ci = Ci[idx];
  float wr = wre[n], wi = wim[n];
  Cpr[idx] = cr * wr - ci * wi;
  Cpi[idx] = cr * wi + ci * wr;
}

// ---------------- S[n,l] = exp(Lam_n l), zero-padded beyond cut, l < SLEN ----------------
__global__ __launch_bounds__(256) void sbuild_kernel(const float* __restrict__ lamr,
                                                     const double* __restrict__ lamid,
                                                     const int* __restrict__ cut,
                                                     float* __restrict__ Sr,
                                                     float* __restrict__ Si) {
  int n = blockIdx.y;
  int l = blockIdx.x * 256 + threadIdx.x;
  float sr = 0.f, si = 0.f;
  if (l < cut[n]) {
    float mag = expf(lamr[n] * (float)l);
    double ph = lamid[n] * (double)l;
    const double tp = 6.283185307179586476925287;
    const double itp = 1.0 / 6.283185307179586476925287;
    ph -= floor(ph * itp) * tp;
    float cs, sn; sincosf((float)ph, &sn, &cs);
    sr = mag * cs; si = mag * sn;
  }
  Sr[(size_t)n * SLEN + l] = sr;
  Si[(size_t)n * SLEN + l] = si;
}

// ---------------- per-l-tile active-mode compaction ----------------
#define KB4_LT 256
#define NTILE (SLEN / KB4_LT)   // 16
__global__ __launch_bounds__(256) void modelist_kernel(const int* __restrict__ cut,
                                                       int* __restrict__ mlist,
                                                       int* __restrict__ mcount) {
  __shared__ int cnt;
  int t = blockIdx.x;
  int l0 = t * KB4_LT;
  int tid = threadIdx.x;
  if (tid == 0) cnt = 0;
  __syncthreads();
  for (int n = tid; n < NMODE; n += 256) {
    if (cut[n] > l0) {
      int p = atomicAdd(&cnt, 1);
      mlist[t * NMODE + p] = n;
    }
  }
  __syncthreads();
  if (tid == 0) mcount[t] = cnt;
}

// ---------------- KT[d,l] = sum_{active n} Cpr[d,n]*Sr[n,l] - Cpi[d,n]*Si[n,l] ----------------
// Grid (NTILE l-tiles, D/KB4_DT d-tiles); branch-free compacted mode loop.
#define KB4_DT 8
__global__ __launch_bounds__(256) void kbuild4_kernel(const float* __restrict__ Sr,
                                                      const float* __restrict__ Si,
                                                      const float* __restrict__ Cpr,
                                                      const float* __restrict__ Cpi,
                                                      const int* __restrict__ mlist,
                                                      const int* __restrict__ mcount,
                                                      float* __restrict__ KT) {
  __shared__ int sml[NMODE];
  __shared__ float sCr[NMODE][KB4_DT], sCi[NMODE][KB4_DT];
  int t = blockIdx.x;
  int d0 = blockIdx.y * KB4_DT;
  int tid = threadIdx.x;
  int nact = mcount[t];
  for (int i = tid; i < nact; i += 256) sml[i] = mlist[t * NMODE + i];
  __syncthreads();
  for (int i = tid; i < nact * KB4_DT; i += 256) {
    int mi = i >> 3, dd = i & 7;
    int n = sml[mi];
    sCr[mi][dd] = Cpr[(size_t)(d0 + dd) * NMODE + n];
    sCi[mi][dd] = Cpi[(size_t)(d0 + dd) * NMODE + n];
  }
  __syncthreads();
  int l = t * KB4_LT + tid;
  float acc[KB4_DT];
  #pragma unroll
  for (int dd = 0; dd < KB4_DT; ++dd) acc[dd] = 0.f;
  for (int i = 0; i < nact; ++i) {
    int n = sml[i];
    float sr = Sr[(size_t)n * SLEN + l];
    float si = Si[(size_t)n * SLEN + l];
    #pragma unroll
    for (int dd = 0; dd < KB4_DT; ++dd)
      acc[dd] += sr * sCr[i][dd] - si * sCi[i][dd];
  }
  #pragma unroll
  for (int dd = 0; dd < KB4_DT; ++dd)
    KT[(size_t)(d0 + dd) * SLEN + l] = acc[dd];
}

// ---------------- 8192-pt complex Stockham FFT in LDS ----------------
// natural order in/out; result ends in bufB. sign=-1 fwd, +1 inv (unnormalized).
// twH[Ls+p] = (cos(pi p/Ls), +sin(pi p/Ls)); effective twiddle = (w.x, sign*w.y).
__device__ __forceinline__ void fft8192_core(float2* bufA, float2* bufB,
                                             const float2* __restrict__ twH,
                                             int tid, float sign) {
  float2* src = bufA;
  float2* dst = bufB;
  #pragma unroll 1
  for (int s = 0; s < 13; ++s) {
    int Ls = 1 << s;
    __syncthreads();
    #pragma unroll
    for (int it = 0; it < 4; ++it) {
      int j = tid + it * 1024;            // butterfly id < 4096
      int p = j & (Ls - 1);
      int q = j >> s;
      float2 w = twH[Ls + p];
      float wr = w.x, wi = sign * w.y;    // fwd: e^{-ia}, inv: e^{+ia}
      float2 a = src[j];
      float2 b = src[j + 4096];
      float br = wr * b.x - wi * b.y;
      float bi = wr * b.y + wi * b.x;
      int o = (q << (s + 1)) + p;
      dst[o]      = make_float2(a.x + br, a.y + bi);
      dst[o + Ls] = make_float2(a.x - br, a.y - bi);
    }
    float2* tsw = src; src = dst; dst = tsw;
  }
  __syncthreads();
}

// ---------------- Kf[d,k] = rfft16384(K_T[d]) / 8192, k=0..8192 ----------------
__global__ __launch_bounds__(1024) void kf_fft_kernel(const float* __restrict__ KT,
                                                      const float2* __restrict__ twH,
                                                      const float2* __restrict__ twR,
                                                      float2* __restrict__ Kf) {
  __shared__ float2 bufA[MFFT];
  __shared__ float2 bufB[MFFT];
  int d = blockIdx.x;
  int tid = threadIdx.x;
  const float2* row = (const float2*)(KT + (size_t)d * SLEN);
  for (int j = tid; j < MFFT; j += 1024)
    bufA[j] = (j < SLEN / 2) ? row[j] : make_float2(0.f, 0.f);
  fft8192_core(bufA, bufB, twH, tid, -1.f);   // Z in bufB
  const float scale = 1.0f / 8192.0f;         // fold inverse-FFT 1/8192 here
  float2* out = Kf + (size_t)d * KF_STRIDE;
  for (int k = tid; k <= 4096; k += 1024) {
    if (k == 0) {
      float2 z0 = bufB[0];
      out[0]    = make_float2((z0.x + z0.y) * scale, 0.f);
      out[8192] = make_float2((z0.x - z0.y) * scale, 0.f);
    } else {
      float2 zk = bufB[k];
      float2 zm = bufB[MFFT - k];
      float Ar = 0.5f * (zk.x + zm.x), Ai = 0.5f * (zk.y - zm.y);
      float Br = 0.5f * (zk.x - zm.x), Bi = 0.5f * (zk.y + zm.y);
      float2 t = twR[k];
      float c = t.x, sn = t.y;
      float e1r = sn * Br - c * Bi;
      float e1i = sn * Bi + c * Br;
      out[k]        = make_float2((Ar - e1r) * scale, (Ai - e1i) * scale);
      out[MFFT - k] = make_float2((Ar + e1r) * scale, (-Ai - e1i) * scale);
    }
  }
}

// ---------------- conv: y = irfft(rfft(u) * Kf) + u*pD, in-place over uT row ----------------
__global__ __launch_bounds__(1024) void conv_fft_kernel(float* __restrict__ uT,
                                                        const float2* __restrict__ twH,
                                                        const float2* __restrict__ twR,
                                                        const float2* __restrict__ Kf,
                                                        const float* __restrict__ pD) {
  __shared__ float2 bufA[MFFT];
  __shared__ float2 bufB[MFFT];
  int wg = blockIdx.x;
  int b = wg >> 10, d = wg & (DDIM - 1);
  int tid = threadIdx.x;
  float2* row = (float2*)(uT + ((size_t)b * DDIM + d) * LLEN);
  for (int j = tid; j < MFFT; j += 1024)
    bufA[j] = (j < 4096) ? row[j] : make_float2(0.f, 0.f);
  fft8192_core(bufA, bufB, twH, tid, -1.f);   // Z in bufB
  const float2* kf = Kf + (size_t)d * KF_STRIDE;
  for (int k = tid; k <= 4096; k += 1024) {
    if (k == 0) {
      float2 z0 = bufB[0];
      float U0 = z0.x + z0.y;
      float UM = z0.x - z0.y;
      float Y0 = U0 * kf[0].x;
      float YM = UM * kf[8192].x;
      bufA[0] = make_float2(0.5f * (Y0 + YM), 0.5f * (Y0 - YM));
    } else {
      float2 zk = bufB[k];
      float2 zm = bufB[MFFT - k];
      float Ar = 0.5f * (zk.x + zm.x), Ai = 0.5f * (zk.y - zm.y);
      float Br = 0.5f * (zk.x - zm.x), Bi = 0.5f * (zk.y + zm.y);
      float2 t = twR[k];
      float c = t.x, sn = t.y;
      float e1r = sn * Br - c * Bi;
      float e1i = sn * Bi + c * Br;
      float Ukr = Ar - e1r, Uki = Ai - e1i;      // U[k]
      float Umr = Ar + e1r, Umi = -Ai - e1i;     // U[8192-k]
      float2 kk = kf[k], km = kf[MFFT - k];
      float Ykr = Ukr * kk.x - Uki * kk.y, Yki = Ukr * kk.y + Uki * kk.x;
      float Ymr = Umr * km.x - Umi * km.y, Ymi = Umr * km.y + Umi * km.x;
      float Eyr = 0.5f * (Ykr + Ymr), Eyi = 0.5f * (Yki - Ymi);
      float Byr = 0.5f * (Ykr - Ymr), Byi = 0.5f * (Yki + Ymi);
      bufA[k]        = make_float2(Eyr - sn * Byr - c * Byi, Eyi + c * Byr - sn * Byi);
      bufA[MFFT - k] = make_float2(Eyr + sn * Byr + c * Byi, -Eyi + c * Byr - sn * Byi);
    }
  }
  __syncthreads();
  fft8192_core(bufA, bufB, twH, tid, +1.f);   // z_y in bufB (1/8192 folded into Kf)
  float pdv = pD[d];
  for (int j = tid; j < 4096; j += 1024) {
    float2 uv = row[j];                        // original u (untouched so far)
    float2 yv = bufB[j];
    row[j] = make_float2(yv.x + uv.x * pdv, yv.y + uv.y * pdv);
  }
}

// ---------------- out[b,l,d] = yT[b,d,l] (transpose back) ----------------
__global__ __launch_bounds__(256) void final_kernel(const float* __restrict__ yT,
                                                    float* __restrict__ out) {
  __shared__ float tile[32][33];
  int lt = blockIdx.x * 32, dt = blockIdx.y * 32, b = blockIdx.z;
  int c = threadIdx.x & 31, r0 = threadIdx.x >> 5;
  #pragma unroll
  for (int i = 0; i < 4; i++) {
    int r = r0 + i * 8;   // d within tile
    tile[r][c] = yT[((size_t)b * DDIM + dt + r) * LLEN + lt + c];
  }
  __syncthreads();
  #pragma unroll
  for (int i = 0; i < 4; i++) {
    int r = r0 + i * 8;   // l within tile
    out[((size_t)b * LLEN + lt + r) * DDIM + dt + c] = tile[c][r];
  }
}

extern "C" void kernel_launch(void* const* d_in, const int* in_sizes, int n_in,
                              void* d_out, int out_size, void* d_ws, size_t ws_size,
                              hipStream_t stream) {
  (void)in_sizes; (void)n_in; (void)out_size;
  if (ws_size < WS_NEED) return;   // safety: fail cleanly (wrong output) instead of faulting
  const float* x     = (const float*)d_in[0];
  const float* Lr    = (const float*)d_in[1];
  const float* Li    = (const float*)d_in[2];
  const float* Cr    = (const float*)d_in[3];
  const float* Ci    = (const float*)d_in[4];
  const float* pD    = (const float*)d_in[5];
  const float* gamma = (const float*)d_in[6];
  const float* beta  = (const float*)d_in[7];
  float* out = (float*)d_out;
  char* ws = (char*)d_ws;

  float*  UT    = (float*)(ws + OFF_UT);
  float2* KF    = (float2*)(ws + OFF_KF);
  float*  SRb   = (float*)(ws + OFF_SR);    // overlaid on KF region
  float*  SIb   = (float*)(ws + OFF_SI);    // overlaid on KF region
  float*  KT    = (float*)(ws + OFF_KT);
  float*  CPR   = (float*)(ws + OFF_CPR);
  float*  CPI   = (float*)(ws + OFF_CPI);
  float*  MEAN  = (float*)(ws + OFF_MEAN);
  float*  RSTD  = (float*)(ws + OFF_RSTD);
  float*  LAMR  = (float*)(ws + OFF_LAMR);
  double* LAMID = (double*)(ws + OFF_LAMID);
  float*  WRe   = (float*)(ws + OFF_WR);
  float*  WIm   = (float*)(ws + OFF_WI);
  int*    CUT   = (int*)(ws + OFF_CUT);
  float2* TWH   = (float2*)(ws + OFF_TW);
  float2* TWR   = (float2*)(ws + OFF_TWR);
  int*    MLIST = (int*)(ws + OFF_MLIST);
  int*    MCNT  = (int*)(ws + OFF_MCNT);

  ln_stats_kernel<<<NB * LLEN, 256, 0, stream>>>(x, MEAN, RSTD);
  transpose_ln_kernel<<<dim3(LLEN / 32, DDIM / 32, NB), 256, 0, stream>>>(x, MEAN, RSTD, gamma, beta, UT);
  build_tables_kernel<<<67, 256, 0, stream>>>(Lr, Li, LAMR, LAMID, WRe, WIm, CUT, TWH, TWR);
  cprime_kernel<<<(DDIM * NMODE) / 256, 256, 0, stream>>>(Cr, Ci, WRe, WIm, CPR, CPI);
  sbuild_kernel<<<dim3(SLEN / 256, NMODE), 256, 0, stream>>>(LAMR, LAMID, CUT, SRb, SIb);
  modelist_kernel<<<NTILE, 256, 0, stream>>>(CUT, MLIST, MCNT);
  kbuild4_kernel<<<dim3(NTILE, DDIM / KB4_DT), 256, 0, stream>>>(SRb, SIb, CPR, CPI, MLIST, MCNT, KT);
  kf_fft_kernel<<<DDIM, 1024, 0, stream>>>(KT, TWH, TWR, KF);   // KF overwrites S region (S dead now)
  conv_fft_kernel<<<NB * DDIM, 1024, 0, stream>>>(UT, TWH, TWR, KF, pD);
  final_kernel<<<dim3(LLEN / 32, DDIM / 32, NB), 256, 0, stream>>>(UT, out);
}

// Round 8
// 483.497 us; speedup vs baseline: 1.8523x; 1.1648x over previous
//
#include <hip/hip_runtime.h>
#include <math.h>

#define LLEN 8192
#define DDIM 1024
#define NB   2
#define NMODE 512
#define MFFT 8192
#define SLEN 4096        // truncated kernel length (K[l]=0 beyond; worst-case e^-20)
#define KF_STRIDE 8208   // float2 per Kf row (8193 used)

// padded LDS index: +1 float2 per 16 (spreads small-stride FFT writes across bank pairs)
#define PIDX(i) ((i) + ((i) >> 4))
#define FBUF 8704        // PIDX(8191)=8702 -> 8704 float2 per buffer (69,632 B)

// ---------------- workspace layout (bytes), total ~172.4 MB ----------------
#define OFF_UT   ((size_t)0)            // u_T [B,D,L] f32 (y+res in place)  67,108,864
#define OFF_KF   ((size_t)67108864)     // Kf [D,KF_STRIDE] float2           67,239,936
                                        //   (Sr/Si [512][4096] f32 overlaid here
                                        //    before kf_fft runs: 8 MB x2)
#define OFF_KT   ((size_t)134348800)    // K_T [D][SLEN] f32                 16,777,216
#define OFF_CPR  ((size_t)167903232)    // C'r [D,N] f32                      2,097,152
#define OFF_CPI  ((size_t)170000384)    // C'i [D,N] f32                      2,097,152
#define OFF_MEAN ((size_t)172097536)    // mean [B,L] f32                        65,536
#define OFF_RSTD ((size_t)172163072)    // rstd [B,L] f32                        65,536
#define OFF_LAMR ((size_t)172228608)    // f32[512]
#define OFF_LAMID ((size_t)172230656)   // f64[512] (4096 B)
#define OFF_WR   ((size_t)172234752)    // f32[512]
#define OFF_WI   ((size_t)172236800)    // f32[512]
#define OFF_CUT  ((size_t)172238848)    // int[512]
#define OFF_TW   ((size_t)172240896)    // twH: 8192 float2 (hierarchical)      65,536
#define OFF_TWR  ((size_t)172306432)    // 8193 float2 (2pi k/16384)            65,544
#define OFF_MLIST ((size_t)172371976)   // int[16][512] per-l-tile active modes  32,768
#define OFF_MCNT  ((size_t)172404744)   // int[16]                                   64
#define WS_NEED  ((size_t)172404808)

// Sr/Si overlay inside the KF region (dead until kf_fft writes KF)
#define OFF_SR   OFF_KF
#define OFF_SI   (OFF_KF + (size_t)(NMODE * SLEN * 4))

// ---------------- LayerNorm stats: mean/rstd per (b,l) row ----------------
__global__ __launch_bounds__(256) void ln_stats_kernel(const float* __restrict__ x,
                                                       float* __restrict__ mean,
                                                       float* __restrict__ rstd) {
  __shared__ float red[16];
  int row = blockIdx.x;            // b*L + l
  int tid = threadIdx.x;
  const float4* xr = (const float4*)(x + (size_t)row * DDIM);
  float4 v = xr[tid];
  float s = v.x + v.y + v.z + v.w;
  float q = v.x*v.x + v.y*v.y + v.z*v.z + v.w*v.w;
  #pragma unroll
  for (int off = 32; off; off >>= 1) { s += __shfl_down(s, off); q += __shfl_down(q, off); }
  int wid = tid >> 6;
  if ((tid & 63) == 0) { red[wid] = s; red[8 + wid] = q; }
  __syncthreads();
  if (tid == 0) {
    float ts = red[0] + red[1] + red[2] + red[3];
    float tq = red[8] + red[9] + red[10] + red[11];
    float m = ts * (1.0f / DDIM);
    float var = tq * (1.0f / DDIM) - m * m;
    mean[row] = m;
    rstd[row] = rsqrtf(var + 1e-5f);
  }
}

// ---------------- fused LN + transpose: x[B,L,D] -> uT[B,D,L] ----------------
__global__ __launch_bounds__(256) void transpose_ln_kernel(const float* __restrict__ x,
                                                           const float* __restrict__ mean,
                                                           const float* __restrict__ rstd,
                                                           const float* __restrict__ gamma,
                                                           const float* __restrict__ beta,
                                                           float* __restrict__ uT) {
  __shared__ float tile[32][33];
  int lt = blockIdx.x * 32, dt = blockIdx.y * 32, b = blockIdx.z;
  int c = threadIdx.x & 31, r0 = threadIdx.x >> 5;
  float gv = gamma[dt + c], bv = beta[dt + c];
  #pragma unroll
  for (int i = 0; i < 4; i++) {
    int r = r0 + i * 8;   // l within tile
    float m = mean[(size_t)b * LLEN + lt + r];
    float rs = rstd[(size_t)b * LLEN + lt + r];
    float xv = x[((size_t)b * LLEN + lt + r) * DDIM + dt + c];
    tile[r][c] = (xv - m) * rs * gv + bv;
  }
  __syncthreads();
  #pragma unroll
  for (int i = 0; i < 4; i++) {
    int r = r0 + i * 8;   // d within tile
    uT[((size_t)b * DDIM + dt + r) * LLEN + lt + c] = tile[c][r];
  }
}

// ---------------- params + twiddle tables (all one-time, double precision) ----------------
__global__ void build_tables_kernel(const float* __restrict__ Lr, const float* __restrict__ Li,
                                    float* lamr, double* lamid, float* wre, float* wim, int* cut,
                                    float2* twH, float2* twR) {
  int gid = blockIdx.x * 256 + threadIdx.x;
  if (gid < NMODE) {
    double lr = (double)Lr[gid], li = (double)Li[gid];
    double ar = -exp(lr);      // Re(Lam)  (negative)
    double ai = exp(li);       // Im(Lam)
    lamr[gid] = (float)ar;
    lamid[gid] = ai;
    double em = exp(ar);
    double cs = cos(ai), sn = sin(ai);
    double er = em * cs - 1.0;     // exp(Lam) - 1
    double ei = em * sn;
    double den = ar * ar + ai * ai;
    wre[gid] = (float)((er * ar + ei * ai) / den);   // (exp(Lam)-1)/Lam
    wim[gid] = (float)((ei * ar - er * ai) / den);
    int co = (int)(40.0 / (-ar)) + 1;                // exp(ar*l) < e^-40 beyond
    cut[gid] = co > SLEN ? SLEN : co;                // clamp to truncated domain
  }
  int j = gid - NMODE;
  if (j >= 0 && j < 8192) {
    // hierarchical twiddle: twH[Ls + p] = (cos(pi*p/Ls), +sin(pi*p/Ls)).
    // Applied as (w.x, sign*w.y): sign=-1 (fwd) -> e^{-i a}, sign=+1 (inv) -> e^{+i a}.
    if (j == 0) {
      twH[0] = make_float2(1.f, 0.f);
    } else {
      int lev = 31 - __clz(j);
      int Ls = 1 << lev;
      int p = j - Ls;
      double a = 3.14159265358979323846264338 * (double)p / (double)Ls;
      twH[j] = make_float2((float)cos(a), (float)sin(a));
    }
  }
  int k = gid - (NMODE + 8192);
  if (k >= 0 && k <= 8192) {
    double a = 6.283185307179586476925287 * (double)k / 16384.0;
    twR[k] = make_float2((float)cos(a), (float)sin(a));
  }
}

// ---------------- C' = (Cr + iCi) * W ----------------
__global__ __launch_bounds__(256) void cprime_kernel(const float* __restrict__ Cr,
                                                     const float* __restrict__ Ci,
                                                     const float* __restrict__ wre,
                                                     const float* __restrict__ wim,
                                                     float* __restrict__ Cpr,
                                                     float* __restrict__ Cpi) {
  int idx = blockIdx.x * 256 + threadIdx.x;   // d*N + n
  int n = idx & (NMODE - 1);
  float cr = Cr[idx], ci = Ci[idx];
  float wr = wre[n], wi = wim[n];
  Cpr[idx] = cr * wr - ci * wi;
  Cpi[idx] = cr * wi + ci * wr;
}

// ---------------- S[n,l] = exp(Lam_n l), zero-padded beyond cut, l < SLEN ----------------
__global__ __launch_bounds__(256) void sbuild_kernel(const float* __restrict__ lamr,
                                                     const double* __restrict__ lamid,
                                                     const int* __restrict__ cut,
                                                     float* __restrict__ Sr,
                                                     float* __restrict__ Si) {
  int n = blockIdx.y;
  int l = blockIdx.x * 256 + threadIdx.x;
  float sr = 0.f, si = 0.f;
  if (l < cut[n]) {
    float mag = expf(lamr[n] * (float)l);
    double ph = lamid[n] * (double)l;
    const double tp = 6.283185307179586476925287;
    const double itp = 1.0 / 6.283185307179586476925287;
    ph -= floor(ph * itp) * tp;
    float cs, sn; sincosf((float)ph, &sn, &cs);
    sr = mag * cs; si = mag * sn;
  }
  Sr[(size_t)n * SLEN + l] = sr;
  Si[(size_t)n * SLEN + l] = si;
}

// ---------------- per-l-tile active-mode compaction ----------------
#define KB4_LT 256
#define NTILE (SLEN / KB4_LT)   // 16
__global__ __launch_bounds__(256) void modelist_kernel(const int* __restrict__ cut,
                                                       int* __restrict__ mlist,
                                                       int* __restrict__ mcount) {
  __shared__ int cnt;
  int t = blockIdx.x;
  int l0 = t * KB4_LT;
  int tid = threadIdx.x;
  if (tid == 0) cnt = 0;
  __syncthreads();
  for (int n = tid; n < NMODE; n += 256) {
    if (cut[n] > l0) {
      int p = atomicAdd(&cnt, 1);
      mlist[t * NMODE + p] = n;
    }
  }
  __syncthreads();
  if (tid == 0) mcount[t] = cnt;
}

// ---------------- KT[d,l] = sum_{active n} Cpr[d,n]*Sr[n,l] - Cpi[d,n]*Si[n,l] ----------------
#define KB4_DT 8
__global__ __launch_bounds__(256) void kbuild4_kernel(const float* __restrict__ Sr,
                                                      const float* __restrict__ Si,
                                                      const float* __restrict__ Cpr,
                                                      const float* __restrict__ Cpi,
                                                      const int* __restrict__ mlist,
                                                      const int* __restrict__ mcount,
                                                      float* __restrict__ KT) {
  __shared__ int sml[NMODE];
  __shared__ float sCr[NMODE][KB4_DT], sCi[NMODE][KB4_DT];
  int t = blockIdx.x;
  int d0 = blockIdx.y * KB4_DT;
  int tid = threadIdx.x;
  int nact = mcount[t];
  for (int i = tid; i < nact; i += 256) sml[i] = mlist[t * NMODE + i];
  __syncthreads();
  for (int i = tid; i < nact * KB4_DT; i += 256) {
    int mi = i >> 3, dd = i & 7;
    int n = sml[mi];
    sCr[mi][dd] = Cpr[(size_t)(d0 + dd) * NMODE + n];
    sCi[mi][dd] = Cpi[(size_t)(d0 + dd) * NMODE + n];
  }
  __syncthreads();
  int l = t * KB4_LT + tid;
  float acc[KB4_DT];
  #pragma unroll
  for (int dd = 0; dd < KB4_DT; ++dd) acc[dd] = 0.f;
  for (int i = 0; i < nact; ++i) {
    int n = sml[i];
    float sr = Sr[(size_t)n * SLEN + l];
    float si = Si[(size_t)n * SLEN + l];
    #pragma unroll
    for (int dd = 0; dd < KB4_DT; ++dd)
      acc[dd] += sr * sCr[i][dd] - si * sCi[i][dd];
  }
  #pragma unroll
  for (int dd = 0; dd < KB4_DT; ++dd)
    KT[(size_t)(d0 + dd) * SLEN + l] = acc[dd];
}

// ---------------- 8192-pt complex FFT in LDS: 6 radix-4 stages + 1 radix-2 ----------------
// natural order in/out; result ends in buf1. sign=-1 fwd, +1 inv (unnormalized).
// Composition of verified radix-2 stages s,s+1 (L=2^s):
//   x0=src[qL+p], x1=src[+4096], x2=src[+2048], x3=src[+6144]
//   A=x0+w1 x1, C=x0-w1 x1, B=x2+w1 x3, D=x2-w1 x3   (w1=e^{sign i pi p/L})
//   E=w2 B, F=w2 D                                    (w2=e^{sign i pi p/2L})
//   dst[o]=A+E; dst[o+2L]=A-E; dst[o+L]=C+sign*i*F; dst[o+3L]=C-sign*i*F
//   (sign*i*F has components (-sign*Fi, +sign*Fr))
__device__ __forceinline__ void fft8192_core(float2* buf0, float2* buf1,
                                             const float2* __restrict__ twH,
                                             int tid, float sign) {
  float2* src = buf0;
  float2* dst = buf1;
  #pragma unroll 1
  for (int s = 0; s < 12; s += 2) {     // radix-4 stages: L = 1,4,16,64,256,1024
    int L = 1 << s;
    __syncthreads();
    #pragma unroll
    for (int it = 0; it < 2; ++it) {
      int j = tid + it * 1024;          // butterfly id < 2048
      int p = j & (L - 1);
      int q = j >> s;
      float2 w1 = twH[L + p];
      float2 w2 = twH[2 * L + p];
      float w1r = w1.x, w1i = sign * w1.y;
      float w2r = w2.x, w2i = sign * w2.y;
      float2 x0 = src[PIDX(j)];
      float2 x1 = src[PIDX(j + 4096)];
      float2 x2 = src[PIDX(j + 2048)];
      float2 x3 = src[PIDX(j + 6144)];
      float t1r = w1r * x1.x - w1i * x1.y, t1i = w1r * x1.y + w1i * x1.x;
      float t3r = w1r * x3.x - w1i * x3.y, t3i = w1r * x3.y + w1i * x3.x;
      float Ar = x0.x + t1r, Ai = x0.y + t1i;
      float Cr = x0.x - t1r, Ci = x0.y - t1i;
      float Br = x2.x + t3r, Bi = x2.y + t3i;
      float Dr = x2.x - t3r, Di = x2.y - t3i;
      float Er = w2r * Br - w2i * Bi, Ei = w2r * Bi + w2i * Br;
      float Fr = w2r * Dr - w2i * Di, Fi = w2r * Di + w2i * Dr;
      int o = (q << (s + 2)) + p;
      dst[PIDX(o)]         = make_float2(Ar + Er, Ai + Ei);
      dst[PIDX(o + L)]     = make_float2(Cr - sign * Fi, Ci + sign * Fr);  // C + sign*i*F
      dst[PIDX(o + 2*L)]   = make_float2(Ar - Er, Ai - Ei);
      dst[PIDX(o + 3*L)]   = make_float2(Cr + sign * Fi, Ci - sign * Fr);  // C - sign*i*F
    }
    float2* t = src; src = dst; dst = t;
  }
  // final radix-2 stage: Ls = 4096 (reads buf0, writes buf1 after 6 swaps)
  __syncthreads();
  #pragma unroll
  for (int it = 0; it < 4; ++it) {
    int j = tid + it * 1024;            // butterfly id < 4096
    float2 w = twH[4096 + j];
    float wr = w.x, wi = sign * w.y;
    float2 a = src[PIDX(j)];
    float2 b = src[PIDX(j + 4096)];
    float br = wr * b.x - wi * b.y;
    float bi = wr * b.y + wi * b.x;
    dst[PIDX(j)]        = make_float2(a.x + br, a.y + bi);
    dst[PIDX(j + 4096)] = make_float2(a.x - br, a.y - bi);
  }
  __syncthreads();
}

// ---------------- Kf[d,k] = rfft16384(K_T[d]) / 8192, k=0..8192 ----------------
__global__ __launch_bounds__(1024) void kf_fft_kernel(const float* __restrict__ KT,
                                                      const float2* __restrict__ twH,
                                                      const float2* __restrict__ twR,
                                                      float2* __restrict__ Kf) {
  __shared__ float2 bufA[FBUF];
  __shared__ float2 bufB[FBUF];
  int d = blockIdx.x;
  int tid = threadIdx.x;
  const float2* row = (const float2*)(KT + (size_t)d * SLEN);
  for (int j = tid; j < MFFT; j += 1024)
    bufA[PIDX(j)] = (j < SLEN / 2) ? row[j] : make_float2(0.f, 0.f);
  fft8192_core(bufA, bufB, twH, tid, -1.f);   // Z in bufB
  const float scale = 1.0f / 8192.0f;         // fold inverse-FFT 1/8192 here
  float2* out = Kf + (size_t)d * KF_STRIDE;
  for (int k = tid; k <= 4096; k += 1024) {
    if (k == 0) {
      float2 z0 = bufB[PIDX(0)];
      out[0]    = make_float2((z0.x + z0.y) * scale, 0.f);
      out[8192] = make_float2((z0.x - z0.y) * scale, 0.f);
    } else {
      float2 zk = bufB[PIDX(k)];
      float2 zm = bufB[PIDX(MFFT - k)];
      float Ar = 0.5f * (zk.x + zm.x), Ai = 0.5f * (zk.y - zm.y);
      float Br = 0.5f * (zk.x - zm.x), Bi = 0.5f * (zk.y + zm.y);
      float2 t = twR[k];
      float c = t.x, sn = t.y;
      float e1r = sn * Br - c * Bi;
      float e1i = sn * Bi + c * Br;
      out[k]        = make_float2((Ar - e1r) * scale, (Ai - e1i) * scale);
      out[MFFT - k] = make_float2((Ar + e1r) * scale, (-Ai - e1i) * scale);
    }
  }
}

// ---------------- conv: y = irfft(rfft(u) * Kf) + u*pD, in-place over uT row ----------------
__global__ __launch_bounds__(1024) void conv_fft_kernel(float* __restrict__ uT,
                                                        const float2* __restrict__ twH,
                                                        const float2* __restrict__ twR,
                                                        const float2* __restrict__ Kf,
                                                        const float* __restrict__ pD) {
  __shared__ float2 bufA[FBUF];
  __shared__ float2 bufB[FBUF];
  int wg = blockIdx.x;
  int b = wg >> 10, d = wg & (DDIM - 1);
  int tid = threadIdx.x;
  float2* row = (float2*)(uT + ((size_t)b * DDIM + d) * LLEN);
  for (int j = tid; j < MFFT; j += 1024)
    bufA[PIDX(j)] = (j < 4096) ? row[j] : make_float2(0.f, 0.f);
  fft8192_core(bufA, bufB, twH, tid, -1.f);   // Z in bufB
  const float2* kf = Kf + (size_t)d * KF_STRIDE;
  for (int k = tid; k <= 4096; k += 1024) {
    if (k == 0) {
      float2 z0 = bufB[PIDX(0)];
      float U0 = z0.x + z0.y;
      float UM = z0.x - z0.y;
      float Y0 = U0 * kf[0].x;
      float YM = UM * kf[8192].x;
      bufA[PIDX(0)] = make_float2(0.5f * (Y0 + YM), 0.5f * (Y0 - YM));
    } else {
      float2 zk = bufB[PIDX(k)];
      float2 zm = bufB[PIDX(MFFT - k)];
      float Ar = 0.5f * (zk.x + zm.x), Ai = 0.5f * (zk.y - zm.y);
      float Br = 0.5f * (zk.x - zm.x), Bi = 0.5f * (zk.y + zm.y);
      float2 t = twR[k];
      float c = t.x, sn = t.y;
      float e1r = sn * Br - c * Bi;
      float e1i = sn * Bi + c * Br;
      float Ukr = Ar - e1r, Uki = Ai - e1i;      // U[k]
      float Umr = Ar + e1r, Umi = -Ai - e1i;     // U[8192-k]
      float2 kk = kf[k], km = kf[MFFT - k];
      float Ykr = Ukr * kk.x - Uki * kk.y, Yki = Ukr * kk.y + Uki * kk.x;
      float Ymr = Umr * km.x - Umi * km.y, Ymi = Umr * km.y + Umi * km.x;
      float Eyr = 0.5f * (Ykr + Ymr), Eyi = 0.5f * (Yki - Ymi);
      float Byr = 0.5f * (Ykr - Ymr), Byi = 0.5f * (Yki + Ymi);
      bufA[PIDX(k)]        = make_float2(Eyr - sn * Byr - c * Byi, Eyi + c * Byr - sn * Byi);
      bufA[PIDX(MFFT - k)] = make_float2(Eyr + sn * Byr + c * Byi, -Eyi + c * Byr - sn * Byi);
    }
  }
  __syncthreads();
  fft8192_core(bufA, bufB, twH, tid, +1.f);   // z_y in bufB (1/8192 folded into Kf)
  float pdv = pD[d];
  for (int j = tid; j < 4096; j += 1024) {
    float2 uv = row[j];                        // original u (untouched so far)
    float2 yv = bufB[PIDX(j)];
    row[j] = make_float2(yv.x + uv.x * pdv, yv.y + uv.y * pdv);
  }
}

// ---------------- out[b,l,d] = yT[b,d,l] (transpose back) ----------------
__global__ __launch_bounds__(256) void final_kernel(const float* __restrict__ yT,
                                                    float* __restrict__ out) {
  __shared__ float tile[32][33];
  int lt = blockIdx.x * 32, dt = blockIdx.y * 32, b = blockIdx.z;
  int c = threadIdx.x & 31, r0 = threadIdx.x >> 5;
  #pragma unroll
  for (int i = 0; i < 4; i++) {
    int r = r0 + i * 8;   // d within tile
    tile[r][c] = yT[((size_t)b * DDIM + dt + r) * LLEN + lt + c];
  }
  __syncthreads();
  #pragma unroll
  for (int i = 0; i < 4; i++) {
    int r = r0 + i * 8;   // l within tile
    out[((size_t)b * LLEN + lt + r) * DDIM + dt + c] = tile[c][r];
  }
}

extern "C" void kernel_launch(void* const* d_in, const int* in_sizes, int n_in,
                              void* d_out, int out_size, void* d_ws, size_t ws_size,
                              hipStream_t stream) {
  (void)in_sizes; (void)n_in; (void)out_size;
  if (ws_size < WS_NEED) return;   // safety: fail cleanly (wrong output) instead of faulting
  const float* x     = (const float*)d_in[0];
  const float* Lr    = (const float*)d_in[1];
  const float* Li    = (const float*)d_in[2];
  const float* Cr    = (const float*)d_in[3];
  const float* Ci    = (const float*)d_in[4];
  const float* pD    = (const float*)d_in[5];
  const float* gamma = (const float*)d_in[6];
  const float* beta  = (const float*)d_in[7];
  float* out = (float*)d_out;
  char* ws = (char*)d_ws;

  float*  UT    = (float*)(ws + OFF_UT);
  float2* KF    = (float2*)(ws + OFF_KF);
  float*  SRb   = (float*)(ws + OFF_SR);    // overlaid on KF region
  float*  SIb   = (float*)(ws + OFF_SI);    // overlaid on KF region
  float*  KT    = (float*)(ws + OFF_KT);
  float*  CPR   = (float*)(ws + OFF_CPR);
  float*  CPI   = (float*)(ws + OFF_CPI);
  float*  MEAN  = (float*)(ws + OFF_MEAN);
  float*  RSTD  = (float*)(ws + OFF_RSTD);
  float*  LAMR  = (float*)(ws + OFF_LAMR);
  double* LAMID = (double*)(ws + OFF_LAMID);
  float*  WRe   = (float*)(ws + OFF_WR);
  float*  WIm   = (float*)(ws + OFF_WI);
  int*    CUT   = (int*)(ws + OFF_CUT);
  float2* TWH   = (float2*)(ws + OFF_TW);
  float2* TWR   = (float2*)(ws + OFF_TWR);
  int*    MLIST = (int*)(ws + OFF_MLIST);
  int*    MCNT  = (int*)(ws + OFF_MCNT);

  ln_stats_kernel<<<NB * LLEN, 256, 0, stream>>>(x, MEAN, RSTD);
  transpose_ln_kernel<<<dim3(LLEN / 32, DDIM / 32, NB), 256, 0, stream>>>(x, MEAN, RSTD, gamma, beta, UT);
  build_tables_kernel<<<67, 256, 0, stream>>>(Lr, Li, LAMR, LAMID, WRe, WIm, CUT, TWH, TWR);
  cprime_kernel<<<(DDIM * NMODE) / 256, 256, 0, stream>>>(Cr, Ci, WRe, WIm, CPR, CPI);
  sbuild_kernel<<<dim3(SLEN / 256, NMODE), 256, 0, stream>>>(LAMR, LAMID, CUT, SRb, SIb);
  modelist_kernel<<<NTILE, 256, 0, stream>>>(CUT, MLIST, MCNT);
  kbuild4_kernel<<<dim3(NTILE, DDIM / KB4_DT), 256, 0, stream>>>(SRb, SIb, CPR, CPI, MLIST, MCNT, KT);
  kf_fft_kernel<<<DDIM, 1024, 0, stream>>>(KT, TWH, TWR, KF);   // KF overwrites S region (S dead now)
  conv_fft_kernel<<<NB * DDIM, 1024, 0, stream>>>(UT, TWH, TWR, KF, pD);
  final_kernel<<<dim3(LLEN / 32, DDIM / 32, NB), 256, 0, stream>>>(UT, out);
}